// Round 1
// baseline (86.013 us; speedup 1.0000x reference)
//
#include <hip/hip_runtime.h>

// Problem constants (fixed by the reference):
//   z: (1, 512, 32, 32) fp32   -> C=512 channels, P=1024 template positions
//   x: (3, 512, 256, 256) fp32 -> B=3, N=65536 pixels
// res[b,n] = 0.001 * sum_c ( sum_p z[c,p] ) * x[b,c,n]
constexpr int C      = 512;
constexpr int P      = 1024;    // 32*32
constexpr int NPIX   = 65536;   // 256*256
constexpr int B      = 3;
constexpr int CCHUNK = 128;     // channels per block (grid.y = C/CCHUNK = 4)

// ---------------------------------------------------------------------------
// Kernel 1: zsum[c] = sum over P of z[c, p].  One wave (64 lanes) per channel.
// Lane l reads float4s at [c*1024 + i*256 + l*4] -> fully coalesced.
// ---------------------------------------------------------------------------
__global__ __launch_bounds__(256) void zsum_kernel(const float* __restrict__ z,
                                                   float* __restrict__ zsum) {
    int gtid = blockIdx.x * blockDim.x + threadIdx.x;
    int wave = gtid >> 6;   // one wave per channel
    int lane = gtid & 63;
    if (wave >= C) return;

    const float4* zp = reinterpret_cast<const float4*>(z + (size_t)wave * P);
    float s = 0.f;
#pragma unroll
    for (int i = 0; i < 4; ++i) {          // 4 iters * 64 lanes * 4 floats = 1024
        float4 v = zp[i * 64 + lane];
        s += (v.x + v.y) + (v.z + v.w);
    }
    // wave-64 butterfly reduce
#pragma unroll
    for (int off = 32; off > 0; off >>= 1)
        s += __shfl_down(s, off, 64);
    if (lane == 0) zsum[wave] = s;
}

// ---------------------------------------------------------------------------
// Kernel 2: out[b,n] += 0.001 * sum_{c in chunk} zsum[c] * x[b,c,n]
// grid.x = pixel blocks (each thread owns one float4 = 4 pixels),
// grid.y = channel chunk. Partials combined with device-scope atomicAdd
// (4 adders per output float -> negligible contention).
// ---------------------------------------------------------------------------
__global__ __launch_bounds__(256) void corr_kernel(const float* __restrict__ x,
                                                   const float* __restrict__ zsum,
                                                   float* __restrict__ out) {
    __shared__ float zs[CCHUNK];
    const int c0 = blockIdx.y * CCHUNK;
    if (threadIdx.x < CCHUNK) zs[threadIdx.x] = zsum[c0 + threadIdx.x];
    __syncthreads();

    const int pix4 = blockIdx.x * blockDim.x + threadIdx.x; // float4 index over b*N/4
    const int b    = pix4 >> 14;        // / (NPIX/4 = 16384)
    const int n4   = pix4 & 16383;      // float4 index within the image

    const float4* xp = reinterpret_cast<const float4*>(x)
                     + (size_t)b  * (C * (NPIX / 4))
                     + (size_t)c0 * (NPIX / 4)
                     + n4;

    float ax = 0.f, ay = 0.f, az = 0.f, aw = 0.f;
#pragma unroll 8
    for (int c = 0; c < CCHUNK; ++c) {
        const float  s = zs[c];                         // LDS broadcast
        const float4 v = xp[(size_t)c * (NPIX / 4)];    // coalesced 16B/lane
        ax += s * v.x;
        ay += s * v.y;
        az += s * v.z;
        aw += s * v.w;
    }

    float* o = out + (size_t)b * NPIX + (size_t)n4 * 4;
    constexpr float OUT_SCALE = 0.001f;
    atomicAdd(o + 0, ax * OUT_SCALE);
    atomicAdd(o + 1, ay * OUT_SCALE);
    atomicAdd(o + 2, az * OUT_SCALE);
    atomicAdd(o + 3, aw * OUT_SCALE);
}

extern "C" void kernel_launch(void* const* d_in, const int* in_sizes, int n_in,
                              void* d_out, int out_size, void* d_ws, size_t ws_size,
                              hipStream_t stream) {
    const float* z   = (const float*)d_in[0];  // (1,512,32,32)
    const float* x   = (const float*)d_in[1];  // (3,512,256,256)
    float*       out = (float*)d_out;          // (3,1,256,256) = 196608 floats
    float*       zsum = (float*)d_ws;          // 512 floats of scratch

    // Output is accumulated atomically across channel chunks -> zero it first.
    // (Harness poisons d_out to 0xAA and never re-poisons between replays.)
    hipMemsetAsync(d_out, 0, (size_t)out_size * sizeof(float), stream);

    // Kernel 1: 512 waves (one per channel) = 32768 threads = 128 blocks.
    zsum_kernel<<<dim3((C * 64) / 256), 256, 0, stream>>>(z, zsum);

    // Kernel 2: (B*NPIX/4) threads over pixels x 4 channel chunks.
    dim3 grid((B * NPIX / 4) / 256, C / CCHUNK);   // (192, 4) = 768 blocks
    corr_kernel<<<grid, 256, 0, stream>>>(x, zsum, out);
}

// Round 2
// 79.090 us; speedup vs baseline: 1.0875x; 1.0875x over previous
//
#include <hip/hip_runtime.h>

// Problem constants (fixed by the reference):
//   z: (1, 512, 32, 32) fp32   -> C=512 channels, P=1024 template positions
//   x: (3, 512, 256, 256) fp32 -> B=3, N=65536 pixels
// res[b,n] = 0.001 * sum_c ( sum_p z[c,p] ) * x[b,c,n]
constexpr int C    = 512;
constexpr int P    = 1024;    // 32*32
constexpr int NPIX = 65536;   // 256*256
constexpr int B    = 3;

// ---------------------------------------------------------------------------
// Kernel 1: zsum[c] = sum over P of z[c, p].  One wave (64 lanes) per channel.
// Lane l reads float4s at [c*1024 + i*256 + l*4] -> fully coalesced.
// ---------------------------------------------------------------------------
__global__ __launch_bounds__(256) void zsum_kernel(const float* __restrict__ z,
                                                   float* __restrict__ zsum) {
    int gtid = blockIdx.x * blockDim.x + threadIdx.x;
    int wave = gtid >> 6;   // one wave per channel
    int lane = gtid & 63;
    if (wave >= C) return;

    const float4* zp = reinterpret_cast<const float4*>(z + (size_t)wave * P);
    float s = 0.f;
#pragma unroll
    for (int i = 0; i < 4; ++i) {          // 4 iters * 64 lanes * 4 floats = 1024
        float4 v = zp[i * 64 + lane];
        s += (v.x + v.y) + (v.z + v.w);
    }
#pragma unroll
    for (int off = 32; off > 0; off >>= 1)
        s += __shfl_down(s, off, 64);
    if (lane == 0) zsum[wave] = s;
}

// ---------------------------------------------------------------------------
// Kernel 2: out[b,n] = 0.001 * sum_{c=0..511} zsum[c] * x[b,c,n]
// One thread per output pixel, full channel loop -> single plain store,
// no atomics, no output pre-zeroing. 768 blocks (3/CU, 12 waves/CU).
// Per channel step a wave reads 64 lanes x 4 B = 256 B contiguous.
// ---------------------------------------------------------------------------
__global__ __launch_bounds__(256) void corr_kernel(const float* __restrict__ x,
                                                   const float* __restrict__ zsum,
                                                   float* __restrict__ out) {
    __shared__ float zs[C];
    for (int i = threadIdx.x; i < C; i += 256) zs[i] = zsum[i];
    __syncthreads();

    const int gid = blockIdx.x * blockDim.x + threadIdx.x; // [0, B*NPIX)
    const int b   = gid >> 16;          // / NPIX
    const int n   = gid & (NPIX - 1);

    const float* xp = x + (size_t)b * C * NPIX + n;

    float acc = 0.f;
#pragma unroll 16
    for (int c = 0; c < C; ++c) {
        acc += zs[c] * xp[(size_t)c * NPIX];   // LDS broadcast * coalesced load
    }

    out[gid] = acc * 0.001f;
}

extern "C" void kernel_launch(void* const* d_in, const int* in_sizes, int n_in,
                              void* d_out, int out_size, void* d_ws, size_t ws_size,
                              hipStream_t stream) {
    const float* z    = (const float*)d_in[0];  // (1,512,32,32)
    const float* x    = (const float*)d_in[1];  // (3,512,256,256)
    float*       out  = (float*)d_out;          // (3,1,256,256) = 196608 floats
    float*       zsum = (float*)d_ws;           // 512 floats of scratch

    // Kernel 1: 512 waves (one per channel) = 128 blocks of 256.
    zsum_kernel<<<dim3((C * 64) / 256), 256, 0, stream>>>(z, zsum);

    // Kernel 2: one thread per output pixel; 768 blocks of 256.
    corr_kernel<<<dim3((B * NPIX) / 256), 256, 0, stream>>>(x, zsum, out);
}